// Round 1
// baseline (500.758 us; speedup 1.0000x reference)
//
#include <hip/hip_runtime.h>
#include <cmath>

#define N_PTS 32768
#define HID   256
#define KTEST 1024
#define TM    16      // points per block
#define CHUNK 512     // points per sk-block chunk

// ---------------------------------------------------------------------------
// Kernel 1: fused MLP forward + analytic 2nd derivative (forward-mode AD).
// States (h, h', h'') kept in LDS as [state][c][p] (p-contiguous for float2
// reads). W streamed from global (L1/L2 resident, 256 KB each).
// Each thread: 2 points x 8 cols x 3 states = 48 accumulators.
// ---------------------------------------------------------------------------
__global__ __launch_bounds__(256) void mlp_kernel(
    const float* __restrict__ x, const float* __restrict__ wq,
    const float* __restrict__ W0, const float* __restrict__ b0,
    const float* __restrict__ W1, const float* __restrict__ b1,
    const float* __restrict__ W2, const float* __restrict__ b2,
    const float* __restrict__ W3, const float* __restrict__ b3,
    float* __restrict__ u_arr, float* __restrict__ d_arr)
{
    __shared__ float hT[3][HID][TM];      // 48 KB
    __shared__ float psum[2][16][TM];     // 2 KB

    const int tid = threadIdx.x;
    const int jg = tid & 31, pg = tid >> 5;
    const int j0 = jg * 8, p0 = pg * 2;
    const int gp0 = blockIdx.x * TM;

    // ---- layer 0 (1 -> 256): elementwise; z'=W0[j], z''=0
    {
        float xp0 = x[gp0 + p0], xp1 = x[gp0 + p0 + 1];
        #pragma unroll
        for (int jj = 0; jj < 8; ++jj) {
            int j = j0 + jj;
            float w = W0[j], b = b0[j];
            float z0 = fmaf(xp0, w, b), z1 = fmaf(xp1, w, b);
            float y0 = tanhf(z0),       y1 = tanhf(z1);
            float s0 = 1.f - y0 * y0,   s1 = 1.f - y1 * y1;
            float yp0 = s0 * w,         yp1 = s1 * w;
            hT[0][j][p0] = y0;               hT[0][j][p0 + 1] = y1;
            hT[1][j][p0] = yp0;              hT[1][j][p0 + 1] = yp1;
            hT[2][j][p0] = -2.f * y0 * yp0 * w;
            hT[2][j][p0 + 1] = -2.f * y1 * yp1 * w;
        }
    }
    __syncthreads();

    // ---- hidden layers 1,2 (256 -> 256): z=hW+b, z'=h'W, z''=h''W
    for (int layer = 0; layer < 2; ++layer) {
        const float* __restrict__ W  = layer ? W2 : W1;
        const float* __restrict__ bb = layer ? b2 : b1;
        float a0[16], a1[16], a2[16];   // [pp*8+jj]
        #pragma unroll
        for (int jj = 0; jj < 8; ++jj) {
            float b = bb[j0 + jj];
            a0[jj] = b;   a0[8 + jj] = b;
            a1[jj] = 0.f; a1[8 + jj] = 0.f;
            a2[jj] = 0.f; a2[8 + jj] = 0.f;
        }
        const float* Wp = W + j0;
        #pragma unroll 4
        for (int c = 0; c < HID; ++c) {
            float4 wa = *(const float4*)(Wp);
            float4 wb = *(const float4*)(Wp + 4);
            Wp += HID;
            float2 h0 = *(const float2*)&hT[0][c][p0];
            float2 h1 = *(const float2*)&hT[1][c][p0];
            float2 h2 = *(const float2*)&hT[2][c][p0];
            float wv[8] = {wa.x, wa.y, wa.z, wa.w, wb.x, wb.y, wb.z, wb.w};
            #pragma unroll
            for (int jj = 0; jj < 8; ++jj) {
                a0[jj]     = fmaf(h0.x, wv[jj], a0[jj]);
                a0[8 + jj] = fmaf(h0.y, wv[jj], a0[8 + jj]);
                a1[jj]     = fmaf(h1.x, wv[jj], a1[jj]);
                a1[8 + jj] = fmaf(h1.y, wv[jj], a1[8 + jj]);
                a2[jj]     = fmaf(h2.x, wv[jj], a2[jj]);
                a2[8 + jj] = fmaf(h2.y, wv[jj], a2[8 + jj]);
            }
        }
        __syncthreads();   // all reads of old hT done
        #pragma unroll
        for (int pp = 0; pp < 2; ++pp) {
            #pragma unroll
            for (int jj = 0; jj < 8; ++jj) {
                float z = a0[pp * 8 + jj], zp = a1[pp * 8 + jj], zpp = a2[pp * 8 + jj];
                float y = tanhf(z);
                float s = 1.f - y * y;
                float yp = s * zp;
                float ypp = fmaf(s, zpp, -2.f * y * yp * zp);  // s*z'' - 2 y (1-y^2) z'^2
                hT[0][j0 + jj][p0 + pp] = y;
                hT[1][j0 + jj][p0 + pp] = yp;
                hT[2][j0 + jj][p0 + pp] = ypp;
            }
        }
        __syncthreads();
    }

    // ---- final layer (256 -> 1): u = h.W3 + b3 ; uxx = h''.W3
    {
        const int p = tid & 15, seg = tid >> 4;
        float su = 0.f, sx = 0.f;
        #pragma unroll
        for (int jj = 0; jj < 16; ++jj) {
            int j = seg * 16 + jj;
            float w3 = W3[j];
            su = fmaf(hT[0][j][p], w3, su);
            sx = fmaf(hT[2][j][p], w3, sx);
        }
        psum[0][seg][p] = su;
        psum[1][seg][p] = sx;
    }
    __syncthreads();
    if (tid < TM) {
        float u = b3[0], uxx = 0.f;
        #pragma unroll
        for (int s = 0; s < 16; ++s) { u += psum[0][s][tid]; uxx += psum[1][s][tid]; }
        int gp = gp0 + tid;
        u_arr[gp] = u;
        float xv = x[gp];
        // d_i = -w_i * (uxx_i + sin(pi x_i));  Rk-Fk = test @ d
        d_arr[gp] = -wq[gp] * (uxx + sinpif(xv));
    }
}

// ---------------------------------------------------------------------------
// Kernel 2: S_k += sum_i sin(pi k x_i) d_i  over a chunk of points.
// Thread owns one k; points staged in LDS (broadcast reads).
// Precision: x = xh + xl with xh having 12 significant bits -> k*xh exact,
// reduced mod 2 exactly; sinpif(r + k*xl) has ~1e-6 phase error.
// ---------------------------------------------------------------------------
__global__ __launch_bounds__(256) void sk_kernel(
    const float* __restrict__ x, const float* __restrict__ d_arr,
    float* __restrict__ Sk)
{
    __shared__ float xs_h[CHUNK], xs_l[CHUNK], ds[CHUNK];
    const int tid = threadIdx.x;
    const int k = blockIdx.x * 256 + tid + 1;     // 1..1024
    const int i0 = blockIdx.y * CHUNK;

    for (int i = tid; i < CHUNK; i += 256) {
        float xv = x[i0 + i];
        float xh = __uint_as_float(__float_as_uint(xv) & 0xFFFFF000u);
        xs_h[i] = xh;
        xs_l[i] = xv - xh;
        ds[i]   = d_arr[i0 + i];
    }
    __syncthreads();

    const float kf = (float)k;
    float s = 0.f;
    #pragma unroll 4
    for (int i = 0; i < CHUNK; ++i) {
        float A   = kf * xs_h[i];                     // exact (<= 22 bits)
        float r   = A - 2.0f * floorf(A * 0.5f);      // A mod 2, exact
        float arg = fmaf(kf, xs_l[i], r);             // in [0, 2.25)
        s = fmaf(sinpif(arg), ds[i], s);
    }
    atomicAdd(&Sk[k - 1], s);
}

// ---------------------------------------------------------------------------
// Kernel 3: loss_interior = mean(Sk^2); loss_boundary = 5*(u0^2 + uN^2)
// ---------------------------------------------------------------------------
__global__ __launch_bounds__(256) void loss_kernel(
    const float* __restrict__ Sk, const float* __restrict__ u_arr,
    float* __restrict__ out)
{
    __shared__ float red[4];
    const int tid = threadIdx.x;
    float s = 0.f;
    for (int i = tid; i < KTEST; i += 256) { float v = Sk[i]; s = fmaf(v, v, s); }
    #pragma unroll
    for (int off = 32; off > 0; off >>= 1) s += __shfl_down(s, off, 64);
    if ((tid & 63) == 0) red[tid >> 6] = s;
    __syncthreads();
    if (tid == 0) {
        float t = red[0] + red[1] + red[2] + red[3];
        out[0] = t * (1.0f / (float)KTEST);
        float u0 = u_arr[0], uN = u_arr[N_PTS - 1];
        out[1] = 5.0f * (u0 * u0 + uN * uN);   // 0.5 * 10 * (...)
    }
}

extern "C" void kernel_launch(void* const* d_in, const int* in_sizes, int n_in,
                              void* d_out, int out_size, void* d_ws, size_t ws_size,
                              hipStream_t stream)
{
    const float* x  = (const float*)d_in[0];
    const float* wq = (const float*)d_in[1];
    const float* W0 = (const float*)d_in[2];
    const float* b0 = (const float*)d_in[3];
    const float* W1 = (const float*)d_in[4];
    const float* b1 = (const float*)d_in[5];
    const float* W2 = (const float*)d_in[6];
    const float* b2 = (const float*)d_in[7];
    const float* W3 = (const float*)d_in[8];
    const float* b3 = (const float*)d_in[9];
    float* out = (float*)d_out;

    float* ws    = (float*)d_ws;
    float* u_arr = ws;                 // 32768
    float* d_arr = ws + N_PTS;         // 32768
    float* Sk    = ws + 2 * N_PTS;     // 1024

    hipMemsetAsync(Sk, 0, KTEST * sizeof(float), stream);
    mlp_kernel<<<N_PTS / TM, 256, 0, stream>>>(x, wq, W0, b0, W1, b1, W2, b2, W3, b3,
                                               u_arr, d_arr);
    sk_kernel<<<dim3(KTEST / 256, N_PTS / CHUNK), 256, 0, stream>>>(x, d_arr, Sk);
    loss_kernel<<<1, 256, 0, stream>>>(Sk, u_arr, out);
}

// Round 2
// 232.100 us; speedup vs baseline: 2.1575x; 2.1575x over previous
//
#include <hip/hip_runtime.h>
#include <cmath>

#define N_PTS 32768
#define HID   256
#define KTEST 1024
#define MB    16       // points per mlp block
#define RS    264      // padded H row stride in bf16 elems (528 B = 16*33: conflict-free b128)
#define CHUNK 128      // points per sk-block chunk

typedef float  f32x4  __attribute__((ext_vector_type(4)));
typedef short  s16x8  __attribute__((ext_vector_type(8)));
typedef __bf16 bf16x8 __attribute__((ext_vector_type(8)));

__device__ __forceinline__ float b2f(unsigned short s) {
    return __uint_as_float(((unsigned int)s) << 16);
}
__device__ __forceinline__ unsigned short f2b_rne(float x) {
    unsigned int b = __float_as_uint(x);
    return (unsigned short)((b + 0x7FFFu + ((b >> 16) & 1u)) >> 16);
}
// exact split: x = hi + lo_f (exact), lo = RNE16(lo_f); dropped lo*lo term ~2^-18
__device__ __forceinline__ void split2(float x, unsigned short& hi, unsigned short& lo) {
    unsigned int b = __float_as_uint(x);
    hi = (unsigned short)(b >> 16);
    float hf = __uint_as_float(b & 0xFFFF0000u);
    lo = f2b_rne(x - hf);
}
__device__ __forceinline__ float fast_tanh(float z) {
    float e = __expf(2.0f * z);          // saturates correctly at +/-inf
    return 1.0f - 2.0f / (e + 1.0f);
}

// ---------------------------------------------------------------------------
// Pre-kernel: W[k][n] fp32 -> Wt_hi/Wt_lo bf16 [n][k] (k-contiguous rows)
// ---------------------------------------------------------------------------
__global__ __launch_bounds__(256) void wsplit_kernel(
    const float* __restrict__ W1, const float* __restrict__ W2,
    unsigned short* __restrict__ Wh1, unsigned short* __restrict__ Wl1,
    unsigned short* __restrict__ Wh2, unsigned short* __restrict__ Wl2)
{
    __shared__ float tile[32][33];
    const float* W = blockIdx.z ? W2 : W1;
    unsigned short* Wh = blockIdx.z ? Wh2 : Wh1;
    unsigned short* Wl = blockIdx.z ? Wl2 : Wl1;
    const int kt = blockIdx.x * 32, nt = blockIdx.y * 32;
    const int c = threadIdx.x & 31, r0 = threadIdx.x >> 5;
    #pragma unroll
    for (int i = 0; i < 4; ++i) {
        int r = r0 + i * 8;
        tile[r][c] = W[(kt + r) * HID + nt + c];
    }
    __syncthreads();
    #pragma unroll
    for (int i = 0; i < 4; ++i) {
        int n = r0 + i * 8;
        float v = tile[c][n];            // = W[kt+c][nt+n]
        unsigned short h, l; split2(v, h, l);
        Wh[(nt + n) * HID + kt + c] = h;
        Wl[(nt + n) * HID + kt + c] = l;
    }
}

// ---------------------------------------------------------------------------
// MLP fwd + u_xx via forward-mode AD, bf16 hi/lo-split MFMA (16x16x32).
// Block: 16 points, 4 waves; wave w owns output cols [w*64, w*64+64).
// States (h,h',h'') in LDS as bf16 hi/lo [state][m][k], row stride RS.
// W streamed from global (pre-transposed bf16 [n][k]).
// ---------------------------------------------------------------------------
__global__ __launch_bounds__(256, 3) void mlp_kernel(
    const float* __restrict__ x, const float* __restrict__ wq,
    const float* __restrict__ W0, const float* __restrict__ b0,
    const float* __restrict__ b1v, const float* __restrict__ b2v,
    const float* __restrict__ W3, const float* __restrict__ b3,
    const unsigned short* __restrict__ W1h, const unsigned short* __restrict__ W1l,
    const unsigned short* __restrict__ W2h, const unsigned short* __restrict__ W2l,
    float* __restrict__ u_arr, float* __restrict__ d_arr)
{
    __shared__ unsigned short Hhi[3][MB][RS];
    __shared__ unsigned short Hlo[3][MB][RS];
    __shared__ float psum[2][16][16];

    const int tid = threadIdx.x;
    const int gp0 = blockIdx.x * MB;

    // ---- layer 0 (1 -> 256): z'=W0[j], z''=0
    {
        const int m = tid & 15, jseg = tid >> 4;
        const float xm = x[gp0 + m];
        #pragma unroll 4
        for (int jj = 0; jj < 16; ++jj) {
            int j = jseg * 16 + jj;
            float w = W0[j];
            float z = fmaf(xm, w, b0[j]);
            float y = fast_tanh(z);
            float s = 1.0f - y * y;
            float yp = s * w;
            float ypp = -2.0f * y * yp * w;
            unsigned short h16, l16;
            split2(y, h16, l16);   Hhi[0][m][j] = h16; Hlo[0][m][j] = l16;
            split2(yp, h16, l16);  Hhi[1][m][j] = h16; Hlo[1][m][j] = l16;
            split2(ypp, h16, l16); Hhi[2][m][j] = h16; Hlo[2][m][j] = l16;
        }
    }
    __syncthreads();

    const int lane = tid & 63, wv = tid >> 6;
    const int q = lane >> 4, ln = lane & 15;

    // ---- hidden layers 1,2 (256 -> 256)
    for (int layer = 0; layer < 2; ++layer) {
        const unsigned short* __restrict__ Wh = layer ? W2h : W1h;
        const unsigned short* __restrict__ Wl = layer ? W2l : W1l;
        const float* __restrict__ bb = layer ? b2v : b1v;

        f32x4 acc[3][4];
        #pragma unroll
        for (int s = 0; s < 3; ++s)
            #pragma unroll
            for (int nt = 0; nt < 4; ++nt)
                acc[s][nt] = (f32x4){0.f, 0.f, 0.f, 0.f};

        for (int k0 = 0; k0 < HID; k0 += 32) {
            s16x8 bh[4], bl[4], ah[3], al[3];
            #pragma unroll
            for (int nt = 0; nt < 4; ++nt) {
                const int off = (wv * 64 + nt * 16 + ln) * HID + k0 + q * 8;
                bh[nt] = *(const s16x8*)(Wh + off);
                bl[nt] = *(const s16x8*)(Wl + off);
            }
            #pragma unroll
            for (int s = 0; s < 3; ++s) {
                ah[s] = *(const s16x8*)&Hhi[s][ln][k0 + q * 8];
                al[s] = *(const s16x8*)&Hlo[s][ln][k0 + q * 8];
            }
            #pragma unroll
            for (int s = 0; s < 3; ++s) {
                #pragma unroll
                for (int nt = 0; nt < 4; ++nt) {
                    acc[s][nt] = __builtin_amdgcn_mfma_f32_16x16x32_bf16(
                        __builtin_bit_cast(bf16x8, ah[s]),
                        __builtin_bit_cast(bf16x8, bh[nt]), acc[s][nt], 0, 0, 0);
                    acc[s][nt] = __builtin_amdgcn_mfma_f32_16x16x32_bf16(
                        __builtin_bit_cast(bf16x8, ah[s]),
                        __builtin_bit_cast(bf16x8, bl[nt]), acc[s][nt], 0, 0, 0);
                    acc[s][nt] = __builtin_amdgcn_mfma_f32_16x16x32_bf16(
                        __builtin_bit_cast(bf16x8, al[s]),
                        __builtin_bit_cast(bf16x8, bh[nt]), acc[s][nt], 0, 0, 0);
                }
            }
        }
        __syncthreads();   // all reads of old H done

        // epilogue: tanh chain, split, store new states
        #pragma unroll
        for (int nt = 0; nt < 4; ++nt) {
            const int c = wv * 64 + nt * 16 + ln;
            const float bias = bb[c];
            #pragma unroll
            for (int i = 0; i < 4; ++i) {
                const int r = q * 4 + i;
                float z   = acc[0][nt][i] + bias;
                float zp  = acc[1][nt][i];
                float zpp = acc[2][nt][i];
                float y  = fast_tanh(z);
                float s  = 1.0f - y * y;
                float yp = s * zp;
                float ypp = fmaf(s, zpp, -2.0f * y * yp * zp);
                unsigned short h16, l16;
                split2(y, h16, l16);   Hhi[0][r][c] = h16; Hlo[0][r][c] = l16;
                split2(yp, h16, l16);  Hhi[1][r][c] = h16; Hlo[1][r][c] = l16;
                split2(ypp, h16, l16); Hhi[2][r][c] = h16; Hlo[2][r][c] = l16;
            }
        }
        __syncthreads();
    }

    // ---- final layer (256 -> 1)
    {
        const int m = tid & 15, seg = tid >> 4;
        float su = 0.f, sx = 0.f;
        #pragma unroll 4
        for (int jj = 0; jj < 16; ++jj) {
            int j = seg * 16 + jj;
            float w3 = W3[j];
            su = fmaf(b2f(Hhi[0][m][j]) + b2f(Hlo[0][m][j]), w3, su);
            sx = fmaf(b2f(Hhi[2][m][j]) + b2f(Hlo[2][m][j]), w3, sx);
        }
        psum[0][seg][m] = su;
        psum[1][seg][m] = sx;
    }
    __syncthreads();
    if (tid < MB) {
        float u = b3[0], uxx = 0.f;
        #pragma unroll
        for (int s2 = 0; s2 < 16; ++s2) { u += psum[0][s2][tid]; uxx += psum[1][s2][tid]; }
        const int gp = gp0 + tid;
        u_arr[gp] = u;
        float xv = x[gp];
        d_arr[gp] = -wq[gp] * (uxx + sinpif(xv));
    }
}

// ---------------------------------------------------------------------------
// S_k += sum_i sin(pi k x_i) d_i over a 128-point chunk (1024 blocks, 4/CU).
// x split hi(12b)/lo so k*x_hi is exact and reduced mod 2 exactly.
// ---------------------------------------------------------------------------
__global__ __launch_bounds__(256) void sk_kernel(
    const float* __restrict__ x, const float* __restrict__ d_arr,
    float* __restrict__ Sk)
{
    __shared__ float xs_h[CHUNK], xs_l[CHUNK], ds[CHUNK];
    const int tid = threadIdx.x;
    const int k = blockIdx.x * 256 + tid + 1;     // 1..1024
    const int i0 = blockIdx.y * CHUNK;

    if (tid < CHUNK) {
        float xv = x[i0 + tid];
        float xh = __uint_as_float(__float_as_uint(xv) & 0xFFFFF000u);
        xs_h[tid] = xh;
        xs_l[tid] = xv - xh;
        ds[tid]   = d_arr[i0 + tid];
    }
    __syncthreads();

    const float kf = (float)k;
    float s = 0.f;
    #pragma unroll 8
    for (int i = 0; i < CHUNK; ++i) {
        float A   = kf * xs_h[i];                     // exact (<= 22 bits)
        float r   = A - 2.0f * floorf(A * 0.5f);      // A mod 2, exact
        float arg = fmaf(kf, xs_l[i], r);
        s = fmaf(sinpif(arg), ds[i], s);
    }
    atomicAdd(&Sk[k - 1], s);
}

// ---------------------------------------------------------------------------
// loss_interior = mean(Sk^2); loss_boundary = 5*(u0^2 + uN^2)
// ---------------------------------------------------------------------------
__global__ __launch_bounds__(256) void loss_kernel(
    const float* __restrict__ Sk, const float* __restrict__ u_arr,
    float* __restrict__ out)
{
    __shared__ float red[4];
    const int tid = threadIdx.x;
    float s = 0.f;
    for (int i = tid; i < KTEST; i += 256) { float v = Sk[i]; s = fmaf(v, v, s); }
    #pragma unroll
    for (int off = 32; off > 0; off >>= 1) s += __shfl_down(s, off, 64);
    if ((tid & 63) == 0) red[tid >> 6] = s;
    __syncthreads();
    if (tid == 0) {
        float t = red[0] + red[1] + red[2] + red[3];
        out[0] = t * (1.0f / (float)KTEST);
        float u0 = u_arr[0], uN = u_arr[N_PTS - 1];
        out[1] = 5.0f * (u0 * u0 + uN * uN);
    }
}

extern "C" void kernel_launch(void* const* d_in, const int* in_sizes, int n_in,
                              void* d_out, int out_size, void* d_ws, size_t ws_size,
                              hipStream_t stream)
{
    const float* x  = (const float*)d_in[0];
    const float* wq = (const float*)d_in[1];
    const float* W0 = (const float*)d_in[2];
    const float* b0 = (const float*)d_in[3];
    const float* W1 = (const float*)d_in[4];
    const float* b1 = (const float*)d_in[5];
    const float* W2 = (const float*)d_in[6];
    const float* b2 = (const float*)d_in[7];
    const float* W3 = (const float*)d_in[8];
    const float* b3 = (const float*)d_in[9];
    float* out = (float*)d_out;

    float* ws    = (float*)d_ws;
    float* u_arr = ws;                 // 32768 f
    float* d_arr = ws + N_PTS;         // 32768 f
    float* Sk    = ws + 2 * N_PTS;     // 1024 f
    unsigned short* W1h = (unsigned short*)(ws + 2 * N_PTS + KTEST);  // 16B-aligned
    unsigned short* W1l = W1h + HID * HID;
    unsigned short* W2h = W1l + HID * HID;
    unsigned short* W2l = W2h + HID * HID;

    hipMemsetAsync(Sk, 0, KTEST * sizeof(float), stream);
    wsplit_kernel<<<dim3(8, 8, 2), 256, 0, stream>>>(W1, W2, W1h, W1l, W2h, W2l);
    mlp_kernel<<<N_PTS / MB, 256, 0, stream>>>(x, wq, W0, b0, b1, b2, W3, b3,
                                               W1h, W1l, W2h, W2l, u_arr, d_arr);
    sk_kernel<<<dim3(KTEST / 256, N_PTS / CHUNK), 256, 0, stream>>>(x, d_arr, Sk);
    loss_kernel<<<1, 256, 0, stream>>>(Sk, u_arr, out);
}

// Round 3
// 187.454 us; speedup vs baseline: 2.6714x; 1.2382x over previous
//
#include <hip/hip_runtime.h>
#include <cmath>

#define N_PTS 32768
#define HID   256
#define KTEST 1024
#define MB    32       // points per mlp block
#define RS    264      // padded H row stride (528 B = 33*16: b128-friendly, 2-way max)
#define CHUNK 128      // points per sk-block chunk

typedef float  f32x4  __attribute__((ext_vector_type(4)));
typedef short  s16x8  __attribute__((ext_vector_type(8)));
typedef __bf16 bf16x8 __attribute__((ext_vector_type(8)));

__device__ __forceinline__ float b2f(unsigned short s) {
    return __uint_as_float(((unsigned int)s) << 16);
}
__device__ __forceinline__ unsigned short f2b_rne(float x) {
    unsigned int b = __float_as_uint(x);
    return (unsigned short)((b + 0x7FFFu + ((b >> 16) & 1u)) >> 16);
}
// exact split for W: x = hi + lo_f (exact), lo = RNE16(lo_f)
__device__ __forceinline__ void split2(float x, unsigned short& hi, unsigned short& lo) {
    unsigned int b = __float_as_uint(x);
    hi = (unsigned short)(b >> 16);
    float hf = __uint_as_float(b & 0xFFFF0000u);
    lo = f2b_rne(x - hf);
}
__device__ __forceinline__ float fast_tanh(float z) {
    float e = __expf(2.0f * z);
    return 1.0f - 2.0f / (e + 1.0f);
}

// ---------------------------------------------------------------------------
// W[k][n] fp32 -> Wh/Wl bf16 [n][k]
// ---------------------------------------------------------------------------
__global__ __launch_bounds__(256) void wsplit_kernel(
    const float* __restrict__ W1, const float* __restrict__ W2,
    unsigned short* __restrict__ Wh1, unsigned short* __restrict__ Wl1,
    unsigned short* __restrict__ Wh2, unsigned short* __restrict__ Wl2)
{
    __shared__ float tile[32][33];
    const float* W = blockIdx.z ? W2 : W1;
    unsigned short* Wh = blockIdx.z ? Wh2 : Wh1;
    unsigned short* Wl = blockIdx.z ? Wl2 : Wl1;
    const int kt = blockIdx.x * 32, nt = blockIdx.y * 32;
    const int c = threadIdx.x & 31, r0 = threadIdx.x >> 5;
    #pragma unroll
    for (int i = 0; i < 4; ++i) {
        int r = r0 + i * 8;
        tile[r][c] = W[(kt + r) * HID + nt + c];
    }
    __syncthreads();
    #pragma unroll
    for (int i = 0; i < 4; ++i) {
        int n = r0 + i * 8;
        float v = tile[c][n];
        unsigned short h, l; split2(v, h, l);
        Wh[(nt + n) * HID + kt + c] = h;
        Wl[(nt + n) * HID + kt + c] = l;
    }
}

// ---------------------------------------------------------------------------
// MLP fwd + u_xx (forward-mode AD). 32 points/block, 4 waves.
// A-side (states) single RNE-bf16 in LDS; B-side (W) hi/lo bf16 from global
// with unroll-2 register prefetch. acc = A*(Bh+Bl): B exact to 2^-17,
// A error 2^-9 unbiased -> loss error ~0.3% << 2% budget.
// ---------------------------------------------------------------------------
__global__ __launch_bounds__(256, 2) void mlp_kernel(
    const float* __restrict__ x, const float* __restrict__ wq,
    const float* __restrict__ W0, const float* __restrict__ b0,
    const float* __restrict__ b1v, const float* __restrict__ b2v,
    const float* __restrict__ W3, const float* __restrict__ b3,
    const unsigned short* __restrict__ W1h, const unsigned short* __restrict__ W1l,
    const unsigned short* __restrict__ W2h, const unsigned short* __restrict__ W2l,
    float* __restrict__ u_arr, float* __restrict__ d_arr)
{
    __shared__ __align__(16) unsigned short Hb[3][MB][RS];   // 50688 B

    const int tid = threadIdx.x;
    const int gp0 = blockIdx.x * MB;

    // ---- layer 0 (1 -> 256)
    {
        const int m = tid & 31, jseg = tid >> 5;   // 8 segs x 32 cols
        const float xm = x[gp0 + m];
        #pragma unroll 8
        for (int jj = 0; jj < 32; ++jj) {
            int j = jseg * 32 + jj;
            float w = W0[j];
            float z = fmaf(xm, w, b0[j]);
            float y = fast_tanh(z);
            float s = 1.0f - y * y;
            float yp = s * w;
            float ypp = -2.0f * y * yp * w;
            Hb[0][m][j] = f2b_rne(y);
            Hb[1][m][j] = f2b_rne(yp);
            Hb[2][m][j] = f2b_rne(ypp);
        }
    }
    __syncthreads();

    const int lane = tid & 63, wv = tid >> 6;
    const int q = lane >> 4, ln = lane & 15;
    const int colbase = wv * 64 + ln;

    // ---- hidden layers 1,2 (256 -> 256)
    for (int layer = 0; layer < 2; ++layer) {
        const unsigned short* __restrict__ Wh = layer ? W2h : W1h;
        const unsigned short* __restrict__ Wl = layer ? W2l : W1l;
        const float* __restrict__ bb = layer ? b2v : b1v;

        f32x4 acc[3][2][4];
        #pragma unroll
        for (int s = 0; s < 3; ++s)
            #pragma unroll
            for (int mf = 0; mf < 2; ++mf)
                #pragma unroll
                for (int nt = 0; nt < 4; ++nt)
                    acc[s][mf][nt] = (f32x4){0.f, 0.f, 0.f, 0.f};

        s16x8 bh[2][4], bl[2][4];
        #pragma unroll
        for (int nt = 0; nt < 4; ++nt) {
            const int off = (colbase + nt * 16) * HID + q * 8;
            bh[0][nt] = *(const s16x8*)(Wh + off);
            bl[0][nt] = *(const s16x8*)(Wl + off);
        }
        int cur = 0;
        for (int k0 = 0; k0 < HID; k0 += 32) {
            const int nxt = cur ^ 1;
            if (k0 + 32 < HID) {
                #pragma unroll
                for (int nt = 0; nt < 4; ++nt) {
                    const int off = (colbase + nt * 16) * HID + (k0 + 32) + q * 8;
                    bh[nxt][nt] = *(const s16x8*)(Wh + off);
                    bl[nxt][nt] = *(const s16x8*)(Wl + off);
                }
            }
            s16x8 av[3][2];
            #pragma unroll
            for (int s = 0; s < 3; ++s)
                #pragma unroll
                for (int mf = 0; mf < 2; ++mf)
                    av[s][mf] = *(const s16x8*)&Hb[s][mf * 16 + ln][k0 + q * 8];
            #pragma unroll
            for (int s = 0; s < 3; ++s)
                #pragma unroll
                for (int mf = 0; mf < 2; ++mf)
                    #pragma unroll
                    for (int nt = 0; nt < 4; ++nt) {
                        acc[s][mf][nt] = __builtin_amdgcn_mfma_f32_16x16x32_bf16(
                            __builtin_bit_cast(bf16x8, av[s][mf]),
                            __builtin_bit_cast(bf16x8, bh[cur][nt]), acc[s][mf][nt], 0, 0, 0);
                        acc[s][mf][nt] = __builtin_amdgcn_mfma_f32_16x16x32_bf16(
                            __builtin_bit_cast(bf16x8, av[s][mf]),
                            __builtin_bit_cast(bf16x8, bl[cur][nt]), acc[s][mf][nt], 0, 0, 0);
                    }
            cur = nxt;
        }
        __syncthreads();   // reads of old H done

        #pragma unroll
        for (int mf = 0; mf < 2; ++mf)
            #pragma unroll
            for (int nt = 0; nt < 4; ++nt) {
                const int c = wv * 64 + nt * 16 + ln;
                const float bias = bb[c];
                #pragma unroll
                for (int i = 0; i < 4; ++i) {
                    const int r = mf * 16 + q * 4 + i;
                    float z   = acc[0][mf][nt][i] + bias;
                    float zp  = acc[1][mf][nt][i];
                    float zpp = acc[2][mf][nt][i];
                    float y  = fast_tanh(z);
                    float s  = 1.0f - y * y;
                    float yp = s * zp;
                    float ypp = fmaf(s, zpp, -2.0f * y * yp * zp);
                    Hb[0][r][c] = f2b_rne(y);
                    Hb[1][r][c] = f2b_rne(yp);
                    Hb[2][r][c] = f2b_rne(ypp);
                }
            }
        __syncthreads();
    }

    // ---- final layer (256 -> 1); psum aliases Hb[1] (h' dead here)
    float* psum = (float*)&Hb[1][0][0];   // [2][8][32] floats = 2 KB
    {
        const int m = tid & 31, seg = tid >> 5;
        float su = 0.f, sx = 0.f;
        #pragma unroll 8
        for (int jj = 0; jj < 32; ++jj) {
            int j = seg * 32 + jj;
            float w3 = W3[j];
            su = fmaf(b2f(Hb[0][m][j]), w3, su);
            sx = fmaf(b2f(Hb[2][m][j]), w3, sx);
        }
        psum[(0 * 8 + seg) * 32 + m] = su;
        psum[(1 * 8 + seg) * 32 + m] = sx;
    }
    __syncthreads();
    if (tid < MB) {
        float u = b3[0], uxx = 0.f;
        #pragma unroll
        for (int s2 = 0; s2 < 8; ++s2) {
            u   += psum[s2 * 32 + tid];
            uxx += psum[(8 + s2) * 32 + tid];
        }
        const int gp = gp0 + tid;
        u_arr[gp] = u;
        float xv = x[gp];
        d_arr[gp] = -wq[gp] * (uxx + sinpif(xv));
    }
}

// ---------------------------------------------------------------------------
// S_k: each thread handles 2 k values (k, k+256 within its half) to amortize
// LDS broadcast reads. x split hi(12b)/lo so k*x_hi exact, mod-2 exact.
// ---------------------------------------------------------------------------
__global__ __launch_bounds__(256) void sk_kernel(
    const float* __restrict__ x, const float* __restrict__ d_arr,
    float* __restrict__ Sk)
{
    __shared__ float xs_h[CHUNK], xs_l[CHUNK], ds[CHUNK];
    const int tid = threadIdx.x;
    const int kA = blockIdx.x * 512 + tid + 1;   // grid.x=2 halves
    const int kB = kA + 256;
    const int i0 = blockIdx.y * CHUNK;

    if (tid < CHUNK) {
        float xv = x[i0 + tid];
        float xh = __uint_as_float(__float_as_uint(xv) & 0xFFFFF000u);
        xs_h[tid] = xh;
        xs_l[tid] = xv - xh;
        ds[tid]   = d_arr[i0 + tid];
    }
    __syncthreads();

    const float kfA = (float)kA, kfB = (float)kB;
    float sA = 0.f, sB = 0.f;
    #pragma unroll 4
    for (int i = 0; i < CHUNK; ++i) {
        float xh = xs_h[i], xl = xs_l[i], dv = ds[i];
        float A1 = kfA * xh;                       // exact (<=22 bits)
        float r1 = A1 - 2.0f * floorf(A1 * 0.5f);
        sA = fmaf(sinpif(fmaf(kfA, xl, r1)), dv, sA);
        float A2 = kfB * xh;
        float r2 = A2 - 2.0f * floorf(A2 * 0.5f);
        sB = fmaf(sinpif(fmaf(kfB, xl, r2)), dv, sB);
    }
    atomicAdd(&Sk[kA - 1], sA);
    atomicAdd(&Sk[kB - 1], sB);
}

// ---------------------------------------------------------------------------
__global__ __launch_bounds__(256) void loss_kernel(
    const float* __restrict__ Sk, const float* __restrict__ u_arr,
    float* __restrict__ out)
{
    __shared__ float red[4];
    const int tid = threadIdx.x;
    float s = 0.f;
    for (int i = tid; i < KTEST; i += 256) { float v = Sk[i]; s = fmaf(v, v, s); }
    #pragma unroll
    for (int off = 32; off > 0; off >>= 1) s += __shfl_down(s, off, 64);
    if ((tid & 63) == 0) red[tid >> 6] = s;
    __syncthreads();
    if (tid == 0) {
        float t = red[0] + red[1] + red[2] + red[3];
        out[0] = t * (1.0f / (float)KTEST);
        float u0 = u_arr[0], uN = u_arr[N_PTS - 1];
        out[1] = 5.0f * (u0 * u0 + uN * uN);
    }
}

extern "C" void kernel_launch(void* const* d_in, const int* in_sizes, int n_in,
                              void* d_out, int out_size, void* d_ws, size_t ws_size,
                              hipStream_t stream)
{
    const float* x  = (const float*)d_in[0];
    const float* wq = (const float*)d_in[1];
    const float* W0 = (const float*)d_in[2];
    const float* b0 = (const float*)d_in[3];
    const float* W1 = (const float*)d_in[4];
    const float* b1 = (const float*)d_in[5];
    const float* W2 = (const float*)d_in[6];
    const float* b2 = (const float*)d_in[7];
    const float* W3 = (const float*)d_in[8];
    const float* b3 = (const float*)d_in[9];
    float* out = (float*)d_out;

    float* ws    = (float*)d_ws;
    float* u_arr = ws;                 // 32768 f
    float* d_arr = ws + N_PTS;         // 32768 f
    float* Sk    = ws + 2 * N_PTS;     // 1024 f
    unsigned short* W1h = (unsigned short*)(ws + 2 * N_PTS + KTEST);
    unsigned short* W1l = W1h + HID * HID;
    unsigned short* W2h = W1l + HID * HID;
    unsigned short* W2l = W2h + HID * HID;

    hipMemsetAsync(Sk, 0, KTEST * sizeof(float), stream);
    wsplit_kernel<<<dim3(8, 8, 2), 256, 0, stream>>>(W1, W2, W1h, W1l, W2h, W2l);
    mlp_kernel<<<N_PTS / MB, 256, 0, stream>>>(x, wq, W0, b0, b1, b2, W3, b3,
                                               W1h, W1l, W2h, W2l, u_arr, d_arr);
    sk_kernel<<<dim3(2, N_PTS / CHUNK), 256, 0, stream>>>(x, d_arr, Sk);
    loss_kernel<<<1, 256, 0, stream>>>(Sk, u_arr, out);
}